// Round 2
// baseline (299.718 us; speedup 1.0000x reference)
//
#include <hip/hip_runtime.h>

// Problem constants (fixed by setup_inputs)
#define Bb 32
#define Cc 4
#define Hh 512
#define Ww 512
#define Tt 64
#define HW (Hh * Ww)                          // 262144
#define NTOT ((long long)Bb * Cc * Hh * Ww)   // 33,554,432 floats per tensor
#define QTOT (Bb * Cc * HW / 4)               // 8,388,608 float4 granules

// Main kernel: 2048 blocks x 256 threads, 16 granules/thread (4 outer x 4 batched)
#define GRID2 2048
#define THREADS2 (GRID2 * 256)                // 524288
#define ITER_TOT (QTOT / THREADS2)            // 16
#define OUTER 4
#define INNER 4

// ws layout:
//   [0 .. GRID2*8)                  : double partials[GRID2]   (16 KiB)
//   [65536 .. 65536 + B*H*8*8)      : uint64 rowmask[B*H][8]   (1 MiB)
#define ROWMASK_OFF 65536

// ---------------------------------------------------------------------------
// Kernel 1: build per-(b,h) column bitmask (512 bits = 8 u64 words per row).
// ---------------------------------------------------------------------------
__global__ __launch_bounds__(256) void build_rowmask_kernel(
    const float* __restrict__ pos,                // [B, T, 2] (x, y)
    unsigned long long* __restrict__ rowmask)     // [B*H][8]
{
    int row = blockIdx.x * 256 + threadIdx.x;     // 0 .. B*H-1
    if (row >= Bb * Hh) return;
    int b = row >> 9;     // row / 512
    int h = row & 511;

    unsigned long long m[8];
#pragma unroll
    for (int i = 0; i < 8; ++i) m[i] = 0ull;

    const float* p = pos + (size_t)b * Tt * 2;
    for (int t = 0; t < Tt; ++t) {
        float x = p[2 * t + 0];
        float y = p[2 * t + 1];
        if (!(x > 0.0f && y > 0.0f)) continue;
        int xp = (int)floorf(x * (float)Ww);
        int yp = (int)floorf(y * (float)Hh);
        if (h < yp - 5 || h >= yp + 5) continue;  // row not covered by this box
        int xlo = xp - 5; if (xlo < 0) xlo = 0;
        int xhi = xp + 5; if (xhi > Ww) xhi = Ww;
        if (xlo >= xhi) continue;
        int w0 = xlo >> 6;
        int w1 = (xhi - 1) >> 6;
        for (int wd = w0; wd <= w1; ++wd) {
            int lo = xlo - (wd << 6); if (lo < 0) lo = 0;
            int hi = xhi - (wd << 6); if (hi > 64) hi = 64;
            m[wd] |= (((1ull << (hi - lo)) - 1ull) << lo);
        }
    }

    unsigned long long* out = rowmask + (size_t)row * 8;
#pragma unroll
    for (int i = 0; i < 8; ++i) out[i] = m[i];
}

// ---------------------------------------------------------------------------
// Kernel 2: weighted squared-difference reduction, FLAT contiguous traversal.
// One granule = one float4 of ONE channel (weight is channel-independent, so
// per-channel masking is identical math). pred/targ are each swept as a single
// contiguous stream: no 1 MB-stride multi-stream aliasing. Loads batched 4
// iterations at a time into static arrays for per-wave MLP.
// Index decode (quads): wq bits[0:7) h bits[7:16) c bits[16:18) b bits[18:24)
// ---------------------------------------------------------------------------
__global__ __launch_bounds__(256, 4) void weighted_sq_sum_kernel(
    const float4* __restrict__ pred4,
    const float4* __restrict__ targ4,
    const unsigned long long* __restrict__ rowmask,
    double* __restrict__ partials)
{
    const int tid0 = blockIdx.x * 256 + threadIdx.x;   // 0 .. THREADS2-1

    double acc = 0.0;
#pragma unroll
    for (int ot = 0; ot < OUTER; ++ot) {
        float4 pa[INNER], ta[INNER];
        unsigned long long wd[INNER];
        unsigned sh[INNER];
#pragma unroll
        for (int it = 0; it < INNER; ++it) {
            int gid = tid0 + (ot * INNER + it) * THREADS2;  // exact cover of QTOT
            pa[it] = pred4[gid];
            ta[it] = targ4[gid];
            int b     = gid >> 18;             // quads per image = 2^18
            int h     = (gid >> 7) & 511;      // quads per row = 128
            int wword = (gid >> 4) & 7;        // (w >> 6), w = (gid&127)<<2
            wd[it] = rowmask[(((size_t)b << 9) + (size_t)h) * 8 + wword];
            sh[it] = (unsigned)((gid & 15) << 2);  // w & 63
        }
#pragma unroll
        for (int it = 0; it < INNER; ++it) {
            float dx = pa[it].x - ta[it].x;
            float dy = pa[it].y - ta[it].y;
            float dz = pa[it].z - ta[it].z;
            float dw = pa[it].w - ta[it].w;
            float sx = dx * dx, sy = dy * dy, sz = dz * dz, sw = dw * dw;
            unsigned bits = (unsigned)((wd[it] >> sh[it]) & 0xFull);
            float tot  = sx + sy + sz + sw;
            float msum = (bits & 1u ? sx : 0.f) + (bits & 2u ? sy : 0.f) +
                         (bits & 4u ? sz : 0.f) + (bits & 8u ? sw : 0.f);
            acc += (double)tot + 3.0 * (double)msum;
        }
    }

    // wave (64-lane) reduction
#pragma unroll
    for (int off = 32; off > 0; off >>= 1)
        acc += __shfl_down(acc, off, 64);

    __shared__ double lsum[4];
    int lane = threadIdx.x & 63;
    int wid  = threadIdx.x >> 6;
    if (lane == 0) lsum[wid] = acc;
    __syncthreads();
    if (threadIdx.x == 0)
        partials[blockIdx.x] = lsum[0] + lsum[1] + lsum[2] + lsum[3];
}

// ---------------------------------------------------------------------------
// Kernel 3: reduce 2048 partials, scale by 1/N, write scalar fp32 output.
// ---------------------------------------------------------------------------
__global__ __launch_bounds__(256) void final_reduce_kernel(
    const double* __restrict__ partials, float* __restrict__ out)
{
    double v = 0.0;
    for (int i = threadIdx.x; i < GRID2; i += 256) v += partials[i];
#pragma unroll
    for (int off = 32; off > 0; off >>= 1)
        v += __shfl_down(v, off, 64);
    __shared__ double lsum[4];
    int lane = threadIdx.x & 63;
    int wid  = threadIdx.x >> 6;
    if (lane == 0) lsum[wid] = v;
    __syncthreads();
    if (threadIdx.x == 0)
        out[0] = (float)((lsum[0] + lsum[1] + lsum[2] + lsum[3]) * (1.0 / (double)NTOT));
}

extern "C" void kernel_launch(void* const* d_in, const int* in_sizes, int n_in,
                              void* d_out, int out_size, void* d_ws, size_t ws_size,
                              hipStream_t stream) {
    const float* pred = (const float*)d_in[0];   // [32,4,512,512] f32
    const float* targ = (const float*)d_in[1];   // [32,4,512,512] f32
    // d_in[2] = text_tokens (unused by the loss)
    const float* pos  = (const float*)d_in[3];   // [32,64,2] f32

    double* partials = (double*)d_ws;
    unsigned long long* rowmask =
        (unsigned long long*)((char*)d_ws + ROWMASK_OFF);
    float* out = (float*)d_out;

    // 1) per-row column bitmasks: B*H = 16384 rows
    build_rowmask_kernel<<<(Bb * Hh + 255) / 256, 256, 0, stream>>>(pos, rowmask);

    // 2) main reduction: flat contiguous sweep, 2048 blocks x 256 threads
    weighted_sq_sum_kernel<<<GRID2, 256, 0, stream>>>(
        (const float4*)pred, (const float4*)targ, rowmask, partials);

    // 3) finalize
    final_reduce_kernel<<<1, 256, 0, stream>>>(partials, out);
}

// Round 3
// 289.874 us; speedup vs baseline: 1.0340x; 1.0340x over previous
//
#include <hip/hip_runtime.h>

// Problem constants (fixed by setup_inputs)
#define Bb 32
#define Cc 4
#define Hh 512
#define Ww 512
#define Tt 64
#define HW (Hh * Ww)                          // 262144
#define NTOT ((long long)Bb * Cc * Hh * Ww)   // 33,554,432 floats per tensor
#define QTOT (Bb * Cc * HW / 4)               // 8,388,608 float4 granules

// Main kernel: 1024 blocks x 256 threads = exactly-resident grid (4 blocks/CU),
// 32 granules/thread = 8 outer batches x 4 granules, double-buffered in regs.
#define GRID2 1024
#define THREADS2 (GRID2 * 256)                // 262144
#define NOUTER 8
#define NBATCH 4                              // 8*4 = 32 = QTOT/THREADS2

// ws layout:
//   [0 .. GRID2*8)                  : double partials[GRID2]   (8 KiB)
//   [65536 .. 65536 + B*H*8*8)      : uint64 rowmask[B*H][8]   (1 MiB)
#define ROWMASK_OFF 65536

// ---------------------------------------------------------------------------
// Kernel 1: build per-(b,h) column bitmask (512 bits = 8 u64 words per row).
// ---------------------------------------------------------------------------
__global__ __launch_bounds__(256) void build_rowmask_kernel(
    const float* __restrict__ pos,                // [B, T, 2] (x, y)
    unsigned long long* __restrict__ rowmask)     // [B*H][8]
{
    int row = blockIdx.x * 256 + threadIdx.x;     // 0 .. B*H-1
    if (row >= Bb * Hh) return;
    int b = row >> 9;     // row / 512
    int h = row & 511;

    unsigned long long m[8];
#pragma unroll
    for (int i = 0; i < 8; ++i) m[i] = 0ull;

    const float* p = pos + (size_t)b * Tt * 2;
    for (int t = 0; t < Tt; ++t) {
        float x = p[2 * t + 0];
        float y = p[2 * t + 1];
        if (!(x > 0.0f && y > 0.0f)) continue;
        int xp = (int)floorf(x * (float)Ww);
        int yp = (int)floorf(y * (float)Hh);
        if (h < yp - 5 || h >= yp + 5) continue;  // row not covered by this box
        int xlo = xp - 5; if (xlo < 0) xlo = 0;
        int xhi = xp + 5; if (xhi > Ww) xhi = Ww;
        if (xlo >= xhi) continue;
        int w0 = xlo >> 6;
        int w1 = (xhi - 1) >> 6;
        for (int wd = w0; wd <= w1; ++wd) {
            int lo = xlo - (wd << 6); if (lo < 0) lo = 0;
            int hi = xhi - (wd << 6); if (hi > 64) hi = 64;
            m[wd] |= (((1ull << (hi - lo)) - 1ull) << lo);
        }
    }

    unsigned long long* out = rowmask + (size_t)row * 8;
#pragma unroll
    for (int i = 0; i < 8; ++i) out[i] = m[i];
}

// ---------------------------------------------------------------------------
// Kernel 2: weighted squared-difference reduction, register double-buffered.
// Flat traversal (granule = one float4 of one channel; weight is channel-
// independent so per-channel masking is identical math).
// Index decode (quads): wq bits[0:7) h bits[7:16) c bits[16:18) b bits[18:24)
// Pipeline: load batch ot+1 into the other buffer, sched_barrier(0), compute
// batch ot. All buffer indices are compile-time constants after full unroll.
// ---------------------------------------------------------------------------
#define ROWM(g) rowmask[(((size_t)((g) >> 18) << 9) + (size_t)(((g) >> 7) & 511)) * 8 \
                        + (size_t)(((g) >> 4) & 7)]

__global__ __launch_bounds__(256, 4) void weighted_sq_sum_kernel(
    const float4* __restrict__ pred4,
    const float4* __restrict__ targ4,
    const unsigned long long* __restrict__ rowmask,
    double* __restrict__ partials)
{
    const int tid0 = blockIdx.x * 256 + (int)threadIdx.x;   // 0 .. THREADS2-1

    float4 pA[NBATCH], tA[NBATCH], pB[NBATCH], tB[NBATCH];
    unsigned long long wA[NBATCH], wB[NBATCH];

    // prologue: batch 0 -> A
#pragma unroll
    for (int k = 0; k < NBATCH; ++k) {
        int g = tid0 + k * THREADS2;
        pA[k] = pred4[g];
        tA[k] = targ4[g];
        wA[k] = ROWM(g);
    }
    __builtin_amdgcn_sched_barrier(0);

    double acc = 0.0;
#pragma unroll
    for (int ot = 0; ot < NOUTER; ++ot) {
        const bool evn = ((ot & 1) == 0);   // compile-time after unroll

        // issue next batch's loads into the OTHER buffer (stay in flight
        // across the compute below; compiler emits counted vmcnt)
        if (ot + 1 < NOUTER) {
#pragma unroll
            for (int k = 0; k < NBATCH; ++k) {
                int g = tid0 + ((ot + 1) * NBATCH + k) * THREADS2;
                if (evn) { pB[k] = pred4[g]; tB[k] = targ4[g]; wB[k] = ROWM(g); }
                else     { pA[k] = pred4[g]; tA[k] = targ4[g]; wA[k] = ROWM(g); }
            }
        }
        __builtin_amdgcn_sched_barrier(0);

        // compute current batch
#pragma unroll
        for (int k = 0; k < NBATCH; ++k) {
            int g = tid0 + (ot * NBATCH + k) * THREADS2;
            float4 a             = evn ? pA[k] : pB[k];
            float4 t             = evn ? tA[k] : tB[k];
            unsigned long long w = evn ? wA[k] : wB[k];
            unsigned sh = (unsigned)((g & 15) << 2);

            float dx = a.x - t.x, dy = a.y - t.y, dz = a.z - t.z, dw = a.w - t.w;
            float sx = dx * dx, sy = dy * dy, sz = dz * dz, sw = dw * dw;
            unsigned bits = (unsigned)((w >> sh) & 0xFull);
            float tot  = sx + sy + sz + sw;
            float msum = (bits & 1u ? sx : 0.f) + (bits & 2u ? sy : 0.f) +
                         (bits & 4u ? sz : 0.f) + (bits & 8u ? sw : 0.f);
            acc += (double)tot + 3.0 * (double)msum;
        }
        __builtin_amdgcn_sched_barrier(0);
    }

    // wave (64-lane) reduction
#pragma unroll
    for (int off = 32; off > 0; off >>= 1)
        acc += __shfl_down(acc, off, 64);

    __shared__ double lsum[4];
    int lane = threadIdx.x & 63;
    int wid  = threadIdx.x >> 6;
    if (lane == 0) lsum[wid] = acc;
    __syncthreads();
    if (threadIdx.x == 0)
        partials[blockIdx.x] = lsum[0] + lsum[1] + lsum[2] + lsum[3];
}

// ---------------------------------------------------------------------------
// Kernel 3: reduce 1024 partials, scale by 1/N, write scalar fp32 output.
// ---------------------------------------------------------------------------
__global__ __launch_bounds__(256) void final_reduce_kernel(
    const double* __restrict__ partials, float* __restrict__ out)
{
    double v = 0.0;
    for (int i = threadIdx.x; i < GRID2; i += 256) v += partials[i];
#pragma unroll
    for (int off = 32; off > 0; off >>= 1)
        v += __shfl_down(v, off, 64);
    __shared__ double lsum[4];
    int lane = threadIdx.x & 63;
    int wid  = threadIdx.x >> 6;
    if (lane == 0) lsum[wid] = v;
    __syncthreads();
    if (threadIdx.x == 0)
        out[0] = (float)((lsum[0] + lsum[1] + lsum[2] + lsum[3]) * (1.0 / (double)NTOT));
}

extern "C" void kernel_launch(void* const* d_in, const int* in_sizes, int n_in,
                              void* d_out, int out_size, void* d_ws, size_t ws_size,
                              hipStream_t stream) {
    const float* pred = (const float*)d_in[0];   // [32,4,512,512] f32
    const float* targ = (const float*)d_in[1];   // [32,4,512,512] f32
    // d_in[2] = text_tokens (unused by the loss)
    const float* pos  = (const float*)d_in[3];   // [32,64,2] f32

    double* partials = (double*)d_ws;
    unsigned long long* rowmask =
        (unsigned long long*)((char*)d_ws + ROWMASK_OFF);
    float* out = (float*)d_out;

    // 1) per-row column bitmasks: B*H = 16384 rows
    build_rowmask_kernel<<<(Bb * Hh + 255) / 256, 256, 0, stream>>>(pos, rowmask);

    // 2) main reduction: exactly-resident grid, deep per-wave MLP
    weighted_sq_sum_kernel<<<GRID2, 256, 0, stream>>>(
        (const float4*)pred, (const float4*)targ, rowmask, partials);

    // 3) finalize
    final_reduce_kernel<<<1, 256, 0, stream>>>(partials, out);
}